// Round 1
// baseline (247.279 us; speedup 1.0000x reference)
//
#include <hip/hip_runtime.h>

// Depthwise 3x3 conv, NHWC, stride 1, SAME padding, depth_multiplier=1, fp32.
// x: (32,112,112,192), w: (3,3,1,192), b: (192), out: (32,112,112,192)

constexpr int Bn = 32;
constexpr int Hn = 112;
constexpr int Wn = 112;
constexpr int Cn = 192;
constexpr int C4 = Cn / 4;  // 48 float4 groups per pixel

__global__ __launch_bounds__(256) void dwconv3x3_kernel(
    const float* __restrict__ x,
    const float* __restrict__ wgt,   // (3,3,1,192)
    const float* __restrict__ bias,  // (192)
    float* __restrict__ out) {
  long i = (long)blockIdx.x * blockDim.x + threadIdx.x;  // one float4 of output
  const long total = (long)Bn * Hn * Wn * C4;
  if (i >= total) return;

  int c4 = (int)(i % C4);
  long t = i / C4;
  int w = (int)(t % Wn); t /= Wn;
  int h = (int)(t % Hn); t /= Hn;
  int b = (int)t;
  int c = c4 * 4;

  float4 acc = *(const float4*)(bias + c);

  const long row_stride = (long)Wn * Cn;
  const long img_base = ((long)b * Hn) * row_stride;

#pragma unroll
  for (int kh = 0; kh < 3; ++kh) {
    int hh = h + kh - 1;
    if (hh < 0 || hh >= Hn) continue;
    const float* xrow = x + img_base + (long)hh * row_stride;
#pragma unroll
    for (int kw = 0; kw < 3; ++kw) {
      int ww = w + kw - 1;
      if (ww < 0 || ww >= Wn) continue;
      float4 xv = *(const float4*)(xrow + (long)ww * Cn + c);
      float4 wv = *(const float4*)(wgt + ((kh * 3 + kw) * Cn + c));
      acc.x = fmaf(xv.x, wv.x, acc.x);
      acc.y = fmaf(xv.y, wv.y, acc.y);
      acc.z = fmaf(xv.z, wv.z, acc.z);
      acc.w = fmaf(xv.w, wv.w, acc.w);
    }
  }

  // Output offset is exactly i*4 because c4 is the innermost index.
  *(float4*)(out + i * 4) = acc;
}

extern "C" void kernel_launch(void* const* d_in, const int* in_sizes, int n_in,
                              void* d_out, int out_size, void* d_ws, size_t ws_size,
                              hipStream_t stream) {
  const float* x = (const float*)d_in[0];
  const float* w = (const float*)d_in[1];
  const float* b = (const float*)d_in[2];
  float* out = (float*)d_out;

  const long total = (long)Bn * Hn * Wn * C4;  // 19,267,584 float4 outputs
  const int block = 256;
  const long grid = (total + block - 1) / block;  // 75,264 blocks

  dwconv3x3_kernel<<<(int)grid, block, 0, stream>>>(x, w, b, out);
}

// Round 3
// 156.818 us; speedup vs baseline: 1.5769x; 1.5769x over previous
//
#include <hip/hip_runtime.h>

// Depthwise 3x3 conv, NHWC, stride 1, SAME, fp32.
// x: (32,112,112,192), w: (3,3,1,192), b: (192), out: (32,112,112,192)
//
// R2: register h-blocking (4 output rows/thread), chunked XCD swizzle,
//     nontemporal output stores (via ext_vector_type — HIP float4 is a class
//     and __builtin_nontemporal_store rejects it).

constexpr int Bn = 32;
constexpr int Hn = 112;
constexpr int Wn = 112;
constexpr int Cn = 192;
constexpr int C4 = Cn / 4;      // 48 float4 groups per pixel
constexpr int HT = 4;           // output rows per thread
constexpr int HTiles = Hn / HT; // 28

typedef float floatx4 __attribute__((ext_vector_type(4)));

__device__ __forceinline__ floatx4 fma4(floatx4 a, floatx4 b, floatx4 c) {
  c.x = fmaf(a.x, b.x, c.x);
  c.y = fmaf(a.y, b.y, c.y);
  c.z = fmaf(a.z, b.z, c.z);
  c.w = fmaf(a.w, b.w, c.w);
  return c;
}

__global__ __launch_bounds__(256) void dwconv3x3_kernel(
    const float* __restrict__ x,
    const float* __restrict__ wgt,   // (3,3,1,192)
    const float* __restrict__ bias,  // (192)
    float* __restrict__ out) {
  // Chunked XCD swizzle: gridDim.x divisible by 8; XCD k gets a contiguous
  // chunk of logical block ids -> vertical-neighbor tiles share one L2.
  int bid = blockIdx.x;
  int chunk = gridDim.x >> 3;                 // blocks per XCD
  int swz = (bid & 7) * chunk + (bid >> 3);
  int i = swz * 256 + (int)threadIdx.x;

  // i -> (b, ht, w, c4), c4 innermost for coalescing.
  int c4 = i % C4;
  int t = i / C4;
  int w = t % Wn; t /= Wn;
  int ht = t % HTiles;
  int b = t / HTiles;
  int c = c4 * 4;
  int h0 = ht * HT;

  floatx4 bv = *(const floatx4*)(bias + c);
  floatx4 acc0 = bv, acc1 = bv, acc2 = bv, acc3 = bv;

  const long row_stride = (long)Wn * Cn;
  const float* xbase = x + ((long)b * Hn) * row_stride + c;  // at h=0,w=0

#pragma unroll
  for (int kw = 0; kw < 3; ++kw) {
    int ww = w + kw - 1;
    if (ww < 0 || ww >= Wn) continue;
    // 3 weight taps for this kw column (L1-resident broadcast).
    floatx4 wv0 = *(const floatx4*)(wgt + ((0 * 3 + kw) * Cn + c));
    floatx4 wv1 = *(const floatx4*)(wgt + ((1 * 3 + kw) * Cn + c));
    floatx4 wv2 = *(const floatx4*)(wgt + ((2 * 3 + kw) * Cn + c));
    const float* col = xbase + (long)ww * Cn;  // at h=0 for this (b, ww, c)

    // Input rows h0-1 .. h0+4 feed outputs h0 .. h0+3.
#pragma unroll
    for (int r = -1; r <= HT; ++r) {
      int hh = h0 + r;
      if (hh < 0 || hh >= Hn) continue;  // only trips at image top/bottom tiles
      floatx4 xv = *(const floatx4*)(col + (long)hh * row_stride);
      // output o uses kh = r - o + 1 in [0,2]
      if (r - 1 >= 0 && r - 1 < HT) {  // o = r-1, kh = 2
        if (r - 1 == 0) acc0 = fma4(xv, wv2, acc0);
        if (r - 1 == 1) acc1 = fma4(xv, wv2, acc1);
        if (r - 1 == 2) acc2 = fma4(xv, wv2, acc2);
        if (r - 1 == 3) acc3 = fma4(xv, wv2, acc3);
      }
      if (r >= 0 && r < HT) {          // o = r, kh = 1
        if (r == 0) acc0 = fma4(xv, wv1, acc0);
        if (r == 1) acc1 = fma4(xv, wv1, acc1);
        if (r == 2) acc2 = fma4(xv, wv1, acc2);
        if (r == 3) acc3 = fma4(xv, wv1, acc3);
      }
      if (r + 1 >= 0 && r + 1 < HT) {  // o = r+1, kh = 0
        if (r + 1 == 0) acc0 = fma4(xv, wv0, acc0);
        if (r + 1 == 1) acc1 = fma4(xv, wv0, acc1);
        if (r + 1 == 2) acc2 = fma4(xv, wv0, acc2);
        if (r + 1 == 3) acc3 = fma4(xv, wv0, acc3);
      }
    }
  }

  // Nontemporal stores: output is never re-read; keep L2 for input rows.
  long obase = (((long)b * Hn + h0) * Wn + w) * C4 + c4;  // float4 index
  floatx4* op = (floatx4*)out + obase;
  const long ostride = (long)Wn * C4;  // one row of float4s
  __builtin_nontemporal_store(acc0, op);
  __builtin_nontemporal_store(acc1, op + ostride);
  __builtin_nontemporal_store(acc2, op + 2 * ostride);
  __builtin_nontemporal_store(acc3, op + 3 * ostride);
}

extern "C" void kernel_launch(void* const* d_in, const int* in_sizes, int n_in,
                              void* d_out, int out_size, void* d_ws, size_t ws_size,
                              hipStream_t stream) {
  const float* x = (const float*)d_in[0];
  const float* w = (const float*)d_in[1];
  const float* b = (const float*)d_in[2];
  float* out = (float*)d_out;

  const long total = (long)Bn * HTiles * Wn * C4;  // 4,816,896 threads
  const int block = 256;
  const int grid = (int)(total / block);           // 18,816 blocks (divisible by 8)

  dwconv3x3_kernel<<<grid, block, 0, stream>>>(x, w, b, out);
}

// Round 4
// 133.144 us; speedup vs baseline: 1.8572x; 1.1778x over previous
//
#include <hip/hip_runtime.h>

// Depthwise 3x3 conv, NHWC, stride 1, SAME, fp32.
// x: (32,112,112,192), w: (3,3,1,192), b: (192), out: (32,112,112,192)
//
// R3: branchless boundary handling; all 18 x-loads + 9 weight-loads issued
//     as one batch (sched_barrier keeps them ahead of the FMAs) to raise
//     memory-level parallelism. R2's 24-VGPR serial chain was the limiter.

constexpr int Bn = 32;
constexpr int Hn = 112;
constexpr int Wn = 112;
constexpr int Cn = 192;
constexpr int C4 = Cn / 4;      // 48 float4 groups per pixel
constexpr int HT = 4;           // output rows per thread
constexpr int HTiles = Hn / HT; // 28

typedef float floatx4 __attribute__((ext_vector_type(4)));

__device__ __forceinline__ floatx4 fma4(floatx4 a, floatx4 b, floatx4 c) {
  c.x = fmaf(a.x, b.x, c.x);
  c.y = fmaf(a.y, b.y, c.y);
  c.z = fmaf(a.z, b.z, c.z);
  c.w = fmaf(a.w, b.w, c.w);
  return c;
}

__global__ __launch_bounds__(256) void dwconv3x3_kernel(
    const float* __restrict__ x,
    const float* __restrict__ wgt,   // (3,3,1,192)
    const float* __restrict__ bias,  // (192)
    float* __restrict__ out) {
  // Chunked XCD swizzle: vertical-neighbor tiles share one XCD L2.
  int bid = blockIdx.x;
  int chunk = gridDim.x >> 3;
  int swz = (bid & 7) * chunk + (bid >> 3);
  int i = swz * 256 + (int)threadIdx.x;

  // i -> (b, ht, w, c4), c4 innermost for coalescing.
  int c4 = i % C4;
  int t = i / C4;
  int w = t % Wn; t /= Wn;
  int ht = t % HTiles;
  int b = t / HTiles;
  int c = c4 * 4;
  int h0 = ht * HT;

  const int row_stride = Wn * Cn;  // 21504 floats per image row
  const float* xbase = x + (long)b * Hn * row_stride + c;

  // Clamped column pointers + validity scales (branchless SAME padding).
  int w0c = max(w - 1, 0);
  int w2c = min(w + 1, Wn - 1);
  float cs0 = (w - 1 >= 0) ? 1.f : 0.f;
  float cs2 = (w + 1 < Wn) ? 1.f : 0.f;
  const float* colp0 = xbase + w0c * Cn;
  const float* colp1 = xbase + w * Cn;
  const float* colp2 = xbase + w2c * Cn;

  // Clamped row offsets + validity (only r=0 at ht==0 / r=5 at ht==27 clamp).
  int roff[6];
  float rs[6];
#pragma unroll
  for (int r = 0; r < 6; ++r) {
    int hh = h0 + r - 1;
    rs[r] = (hh >= 0 && hh < Hn) ? 1.f : 0.f;
    int hc = min(max(hh, 0), Hn - 1);
    roff[r] = hc * row_stride;
  }

  // ---- Batch-issue all 18 input loads into distinct registers ----
  floatx4 xv[6][3];
#pragma unroll
  for (int r = 0; r < 6; ++r) {
    xv[r][0] = *(const floatx4*)(colp0 + roff[r]);
    xv[r][1] = *(const floatx4*)(colp1 + roff[r]);
    xv[r][2] = *(const floatx4*)(colp2 + roff[r]);
  }
  // Weights (small, L1-broadcast).
  floatx4 wv[3][3];
#pragma unroll
  for (int kh = 0; kh < 3; ++kh)
#pragma unroll
    for (int kw = 0; kw < 3; ++kw)
      wv[kh][kw] = *(const floatx4*)(wgt + (kh * 3 + kw) * Cn + c);
  // Keep every load issued before any consumer is scheduled.
  __builtin_amdgcn_sched_barrier(0);

  // Apply boundary validity as multiplies (no divergent branches).
#pragma unroll
  for (int r = 0; r < 6; ++r) {
    xv[r][0] *= rs[r] * cs0;
    xv[r][1] *= rs[r];
    xv[r][2] *= rs[r] * cs2;
  }

  floatx4 bv = *(const floatx4*)(bias + c);
  floatx4 acc0 = bv, acc1 = bv, acc2 = bv, acc3 = bv;
#pragma unroll
  for (int kh = 0; kh < 3; ++kh)
#pragma unroll
    for (int kw = 0; kw < 3; ++kw) {
      acc0 = fma4(xv[0 + kh][kw], wv[kh][kw], acc0);
      acc1 = fma4(xv[1 + kh][kw], wv[kh][kw], acc1);
      acc2 = fma4(xv[2 + kh][kw], wv[kh][kw], acc2);
      acc3 = fma4(xv[3 + kh][kw], wv[kh][kw], acc3);
    }

  // Nontemporal stores: output is never re-read.
  long obase = (((long)b * Hn + h0) * Wn + w) * C4 + c4;  // float4 index
  floatx4* op = (floatx4*)out + obase;
  const long ostride = (long)Wn * C4;
  __builtin_nontemporal_store(acc0, op);
  __builtin_nontemporal_store(acc1, op + ostride);
  __builtin_nontemporal_store(acc2, op + 2 * ostride);
  __builtin_nontemporal_store(acc3, op + 3 * ostride);
}

extern "C" void kernel_launch(void* const* d_in, const int* in_sizes, int n_in,
                              void* d_out, int out_size, void* d_ws, size_t ws_size,
                              hipStream_t stream) {
  const float* x = (const float*)d_in[0];
  const float* w = (const float*)d_in[1];
  const float* b = (const float*)d_in[2];
  float* out = (float*)d_out;

  const long total = (long)Bn * HTiles * Wn * C4;  // 4,816,896 threads
  const int block = 256;
  const int grid = (int)(total / block);           // 18,816 blocks (div by 8)

  dwconv3x3_kernel<<<grid, block, 0, stream>>>(x, w, b, out);
}

// Round 5
// 119.897 us; speedup vs baseline: 2.0624x; 1.1105x over previous
//
#include <hip/hip_runtime.h>
#include <cstdint>

// Depthwise 3x3 conv, NHWC, stride 1, SAME, fp32.
// x: (32,112,112,192), w: (3,3,1,192), b: (192), out: (32,112,112,192)
//
// R5: LDS-staged tiles via global_load_lds (VGPR-free, high-MLP staging).
//     Block = 16w x 16c4 threads, 4 output rows -> 6x18x16 float4 halo tile
//     (27 KB LDS). Consume with lane-contiguous ds_read_b128 (conflict-free).
//     Branchless SAME padding: clamped stage addresses + validity multiplies.

constexpr int Bn = 32, Hn = 112, Wn = 112, Cn = 192, C4 = 48;
constexpr int HT = 4, WT = 16, CT = 16;
constexpr int HTiles = Hn / HT;   // 28
constexpr int WTiles = Wn / WT;   // 7
constexpr int CTiles = C4 / CT;   // 3
constexpr int LR = HT + 2;        // 6 lds rows
constexpr int LW = WT + 2;        // 18 lds cols
constexpr int NF4 = LR * LW * CT; // 1728 float4 = 27648 B
constexpr int NCHUNK = NF4 / 64;  // 27 wave-chunks of 1 KB

typedef float floatx4 __attribute__((ext_vector_type(4)));

__device__ __forceinline__ floatx4 fma4(floatx4 a, floatx4 b, floatx4 c) {
  c.x = fmaf(a.x, b.x, c.x);
  c.y = fmaf(a.y, b.y, c.y);
  c.z = fmaf(a.z, b.z, c.z);
  c.w = fmaf(a.w, b.w, c.w);
  return c;
}

__global__ __launch_bounds__(256, 4) void dwconv3x3_lds(
    const float* __restrict__ x,
    const float* __restrict__ wgt,   // (3,3,1,192)
    const float* __restrict__ bias,  // (192)
    float* __restrict__ out) {
  __shared__ floatx4 lds[NF4];
  int tid = (int)threadIdx.x;
  int lane = tid & 63;
  int wave = tid >> 6;

  // Chunked XCD swizzle: ht-neighbor tiles (stride 21 blocks) share one L2.
  int bid = blockIdx.x;
  int chunk = gridDim.x >> 3;  // 2352
  int sbid = (bid & 7) * chunk + (bid >> 3);
  int c4t = sbid % CTiles; int t = sbid / CTiles;
  int wt = t % WTiles;     t /= WTiles;
  int ht = t % HTiles;     int b = t / HTiles;

  int h0 = ht * HT, w0 = wt * WT;
  int cbase = c4t * (CT * 4);  // float offset of this channel tile
  const float* xb = x + (long)b * Hn * Wn * Cn + cbase;

  // ---- Stage halo tile into LDS: lds[ri][wi][c4i], linear, 1KB per chunk.
  for (int k = wave; k < NCHUNK; k += 4) {
    int linear = k * 64 + lane;
    int c4i = linear & 15;
    int t2 = linear >> 4;         // 0..107
    int wi = t2 % LW;             // 0..17
    int ri = t2 / LW;             // 0..5
    int h = h0 + ri - 1;
    int wg = w0 + wi - 1;
    int hc = min(max(h, 0), Hn - 1);   // clamp; zeroed at consume
    int wc = min(max(wg, 0), Wn - 1);
    const float* src = xb + ((long)hc * Wn + wc) * Cn + c4i * 4;
    __builtin_amdgcn_global_load_lds(
        (const __attribute__((address_space(1))) void*)src,
        (__attribute__((address_space(3))) void*)&lds[k * 64], 16, 0, 0);
  }

  // ---- Weights + bias via L1 while staging flies (VGPR-resident).
  int c4i = tid & 15;
  int wi1 = tid >> 4;            // 0..15; own lds col is wi1+1
  int cofs = cbase + c4i * 4;
  floatx4 wv[3][3];
#pragma unroll
  for (int kh = 0; kh < 3; ++kh)
#pragma unroll
    for (int kw = 0; kw < 3; ++kw)
      wv[kh][kw] = *(const floatx4*)(wgt + (kh * 3 + kw) * Cn + cofs);
  floatx4 bv = *(const floatx4*)(bias + cofs);
  floatx4 acc[HT];
#pragma unroll
  for (int o = 0; o < HT; ++o) acc[o] = bv;

  int wg1 = w0 + wi1;
  float cs0 = (wg1 - 1 >= 0) ? 1.f : 0.f;
  float cs2 = (wg1 + 1 < Wn) ? 1.f : 0.f;

  asm volatile("s_waitcnt vmcnt(0)" ::: "memory");
  __syncthreads();

  // ---- Consume: row-streamed, lane-contiguous ds_read_b128.
#pragma unroll
  for (int r = 0; r < LR; ++r) {
    int h = h0 + r - 1;
    float s1 = (h >= 0 && h < Hn) ? 1.f : 0.f;
    const floatx4* base = &lds[(r * LW + wi1) * CT + c4i];
    floatx4 xv0 = base[0] * (s1 * cs0);
    floatx4 xv1 = base[CT] * s1;
    floatx4 xv2 = base[2 * CT] * (s1 * cs2);
#pragma unroll
    for (int kh = 0; kh < 3; ++kh) {
      int o = r - kh;  // lds row r = input row h0+r-1 feeds output o with kh=r-o
      if (o >= 0 && o < HT) {
        acc[o] = fma4(xv0, wv[kh][0], acc[o]);
        acc[o] = fma4(xv1, wv[kh][1], acc[o]);
        acc[o] = fma4(xv2, wv[kh][2], acc[o]);
      }
    }
  }

  // ---- Nontemporal stores (output never re-read).
  long of4 = (((long)b * Hn + h0) * Wn + wg1) * C4 + c4t * CT + c4i;
  floatx4* op = (floatx4*)out + of4;
  const int ostride = Wn * C4;  // 5376 float4 per output row
#pragma unroll
  for (int o = 0; o < HT; ++o)
    __builtin_nontemporal_store(acc[o], op + (long)o * ostride);
}

extern "C" void kernel_launch(void* const* d_in, const int* in_sizes, int n_in,
                              void* d_out, int out_size, void* d_ws, size_t ws_size,
                              hipStream_t stream) {
  const float* x = (const float*)d_in[0];
  const float* w = (const float*)d_in[1];
  const float* b = (const float*)d_in[2];
  float* out = (float*)d_out;

  const int grid = Bn * HTiles * WTiles * CTiles;  // 18816, divisible by 8
  dwconv3x3_lds<<<grid, 256, 0, stream>>>(x, w, b, out);
}

// Round 6
// 106.937 us; speedup vs baseline: 2.3124x; 1.1212x over previous
//
#include <hip/hip_runtime.h>

// Depthwise 3x3 conv, NHWC, stride 1, SAME, fp32.
// x: (32,112,112,192), w: (3,3,1,192), b: (192), out: (32,112,112,192)
//
// R6: streaming ring-buffer pipeline. Each block processes a 28-row column
//     (7 tiles x 4 rows) of a 16-wide x 16-c4 patch. LDS = 10-row ring of
//     staged halo rows (20 cols x 16 c4 f4 = 5120 B/row, 50 KB total).
//     Per tile: issue next 4 rows via global_load_lds (exactly 5 wave-instrs),
//     counted s_waitcnt vmcnt(9) (never 0 - prefetch + stores stay in flight),
//     raw s_barrier, consume (18 ds_read_b128 + 36 fma4), nt-store, barrier.

constexpr int Bn = 32, Hn = 112, Wn = 112, Cn = 192, C4 = 48;
constexpr int HT = 4, WT = 16, CT = 16;
constexpr int NSTEP = 7;            // tiles per block (28 output rows)
constexpr int HG = 4;               // Hn / (HT*NSTEP)
constexpr int WTiles = 7, CTiles = 3;
constexpr int LW = 20;              // staged halo cols (18 needed; padded so a
                                    // 4-row step = 20 chunks = 5/wave exactly)
constexpr int ROWF4 = LW * CT;      // 320 float4 per staged row
constexpr int ROWB = ROWF4 * 16;    // 5120 bytes
constexpr int RING = 10;            // ring rows: 6 live + 4 in-flight

typedef float floatx4 __attribute__((ext_vector_type(4)));

__device__ __forceinline__ floatx4 fma4(floatx4 a, floatx4 b, floatx4 c) {
  c.x = fmaf(a.x, b.x, c.x);
  c.y = fmaf(a.y, b.y, c.y);
  c.z = fmaf(a.z, b.z, c.z);
  c.w = fmaf(a.w, b.w, c.w);
  return c;
}

__global__ __launch_bounds__(256, 3) void dwconv3x3_stream(
    const float* __restrict__ x,
    const float* __restrict__ wgt,   // (3,3,1,192)
    const float* __restrict__ bias,  // (192)
    float* __restrict__ out) {
  __shared__ floatx4 lds[RING * ROWF4];  // 51200 B
  const int tid = (int)threadIdx.x;
  const int lane = tid & 63;
  const int wave = tid >> 6;

  // Chunked XCD swizzle (2688 % 8 == 0): 21 consecutive sbids share one
  // (b,hg) 30-row input stripe (~3.2 MB) -> same XCD L2.
  int bid = blockIdx.x;
  int chunk = gridDim.x >> 3;  // 336
  int sbid = (bid & 7) * chunk + (bid >> 3);
  int c4t = sbid % CTiles; int t0 = sbid / CTiles;
  int wt = t0 % WTiles;    t0 /= WTiles;
  int hg = t0 % HG;        int b = t0 / HG;

  const int hbase = hg * (HT * NSTEP);
  const int w0 = wt * WT;
  const int cbase = c4t * (CT * 4);
  const float* xb = x + (long)b * Hn * Wn * Cn;

  // Per-lane stage source column offsets (invariant across rows).
  // Stage layout: row-chunk j holds f4 linear [j*64, j*64+64):
  //   wi = linear>>4 (0..19), c4i = linear&15.
  int colOff[5];
  {
    int c4l = lane & 15;
#pragma unroll
    for (int j = 0; j < 5; ++j) {
      int wi = j * 4 + (lane >> 4);
      int wg = w0 + wi - 1;
      int wc = min(max(wg, 0), Wn - 1);  // clamp; w-validity folded into wv
      colOff[j] = wc * Cn + cbase + c4l * 4;
    }
  }

  // This wave stages staged-row 'row' (input h = hbase+row-1): 5 chunks.
  auto stageRow = [&](int row) {
    int h = hbase + row - 1;
    int hc = min(max(h, 0), Hn - 1);
    const float* rowp = xb + (long)hc * (Wn * Cn);
    int slot = row % RING;
    char* ldsbase = (char*)lds + slot * ROWB;
#pragma unroll
    for (int j = 0; j < 5; ++j) {
      __builtin_amdgcn_global_load_lds(
          (const __attribute__((address_space(1))) void*)(rowp + colOff[j]),
          (__attribute__((address_space(3))) void*)(ldsbase + j * 1024),
          16, 0, 0);
    }
  };

  // Prologue: stage rows 0..5 (waves 2,3 duplicate rows 4,5 - benign,
  // keeps per-wave issue count uniform at 10).
  stageRow(wave);
  stageRow(4 + (wave & 1));

  // Weights (L1-broadcast), w-edge validity folded in once.
  const int c4i = tid & 15;
  const int wi1 = tid >> 4;
  const int cofs = cbase + c4i * 4;
  const int wg1 = w0 + wi1;
  const float cs0 = (wg1 >= 1) ? 1.f : 0.f;
  const float cs2 = (wg1 <= Wn - 2) ? 1.f : 0.f;
  floatx4 wv[3][3];
#pragma unroll
  for (int kh = 0; kh < 3; ++kh) {
#pragma unroll
    for (int kw = 0; kw < 3; ++kw)
      wv[kh][kw] = *(const floatx4*)(wgt + (kh * 3 + kw) * Cn + cofs);
    wv[kh][0] *= cs0;
    wv[kh][2] *= cs2;
  }
  const floatx4 bv = *(const floatx4*)(bias + cofs);

  const float sTop = (hg == 0) ? 0.f : 1.f;       // input row hbase-1 validity
  const float sBot = (hg == HG - 1) ? 0.f : 1.f;  // input row hbase+28 validity

  const int ostrideF4 = Wn * C4;  // 5376
  floatx4* outp = (floatx4*)out +
      ((long)b * Hn + hbase) * ostrideF4 + (long)wg1 * C4 + c4t * CT + c4i;

  // Consume vaddr: byte offset (wi1*16 + c4i)*16 == tid*16; kw adds 256 B,
  // slot adds slot*5120 B - both compile-time immediates after unroll.
#pragma unroll
  for (int t = 0; t < NSTEP; ++t) {
    // Issue next step's 4 rows (rows 4t+6..4t+9; last iter = clamped ghosts).
    stageRow(4 * t + 6 + wave);
    // Counted wait: drains exactly the rows tile t needs; keeps the 5 loads
    // just issued (and up to 4 prior stores) in flight.
    if (t == 0) asm volatile("s_waitcnt vmcnt(5)" ::: "memory");
    else        asm volatile("s_waitcnt vmcnt(9)" ::: "memory");
    __builtin_amdgcn_s_barrier();

    floatx4 acc[HT];
#pragma unroll
    for (int o = 0; o < HT; ++o) acc[o] = bv;

#pragma unroll
    for (int r = 0; r < 6; ++r) {
      const int slot = (4 * t + r) % RING;  // compile-time
      const floatx4* base = lds + slot * ROWF4 + wi1 * 16 + c4i;
      floatx4 xv0 = base[0];
      floatx4 xv1 = base[16];
      floatx4 xv2 = base[32];
      if (t == 0 && r == 0) { xv0 *= sTop; xv1 *= sTop; xv2 *= sTop; }
      if (t == NSTEP - 1 && r == 5) { xv0 *= sBot; xv1 *= sBot; xv2 *= sBot; }
#pragma unroll
      for (int kh = 0; kh < 3; ++kh) {
        int o = r - kh;
        if (o >= 0 && o < HT) {
          acc[o] = fma4(xv0, wv[kh][0], acc[o]);
          acc[o] = fma4(xv1, wv[kh][1], acc[o]);
          acc[o] = fma4(xv2, wv[kh][2], acc[o]);
        }
      }
    }

#pragma unroll
    for (int o = 0; o < HT; ++o)
      __builtin_nontemporal_store(acc[o], outp + (long)(4 * t + o) * ostrideF4);

    // All waves done reading this tile's slots before anyone's next-issued
    // loads can land in them (loads issued after this barrier).
    __builtin_amdgcn_s_barrier();
  }
}

extern "C" void kernel_launch(void* const* d_in, const int* in_sizes, int n_in,
                              void* d_out, int out_size, void* d_ws, size_t ws_size,
                              hipStream_t stream) {
  const float* x = (const float*)d_in[0];
  const float* w = (const float*)d_in[1];
  const float* b = (const float*)d_in[2];
  float* out = (float*)d_out;

  const int grid = Bn * HG * WTiles * CTiles;  // 2688, divisible by 8
  dwconv3x3_stream<<<grid, 256, 0, stream>>>(x, w, b, out);
}